// Round 1
// 1653.237 us; speedup vs baseline: 1.3953x; 1.3953x over previous
//
#include <hip/hip_runtime.h>
#include <math.h>

#define BB 2
#define HH 16
#define SS 2048
#define DD 64
#define TQ 8          // q rows per block (16 -> 8: LDS 147 KiB -> 75 KiB => 2 blocks/CU)
#define STRIDE 2052   // score strip row stride (floats): %4==0 for b128, %32==4 to break bank conflicts

typedef __attribute__((ext_vector_type(8))) short bf16x8;
typedef __attribute__((ext_vector_type(4))) float f32x4;
typedef __attribute__((ext_vector_type(4))) int i32x4;

__device__ __forceinline__ unsigned short f2bf(float f) {
    unsigned u = __float_as_uint(f);
    u += 0x7FFF + ((u >> 16) & 1);   // RNE
    return (unsigned short)(u >> 16);
}

// Exact integer-threshold T5 bucket (bidirectional, 32 buckets, max_distance=128).
__device__ __forceinline__ int rel_bucket(int cpq, int mpk) {
    int n = cpq - mpk;            // n = -(mem - ctx)
    int ret = 0;
    if (n < 0) { ret = 16; n = -n; }
    int v;
    if (n < 8) v = n;
    else {
        int j = (n >= 12) + (n >= 16) + (n >= 23) + (n >= 32) +
                (n >= 46) + (n >= 64) + (n >= 91);
        v = 8 + j;
    }
    return ret + v;
}

// Pre-kernel: K f32 -> bf16 once (8 MiB into d_ws). Removes per-block VALU
// re-conversion (K was converted 128x per (b,h) before) and halves K read bytes.
__launch_bounds__(256)
__global__ void conv_k_bf16(const float* __restrict__ src,
                            unsigned short* __restrict__ dst) {
    const size_t i = ((size_t)blockIdx.x * 256 + threadIdx.x) * 8;
    float4 f0 = *(const float4*)(src + i);
    float4 f1 = *(const float4*)(src + i + 4);
    union { bf16x8 v; unsigned short u[8]; } o;
    o.u[0] = f2bf(f0.x); o.u[1] = f2bf(f0.y); o.u[2] = f2bf(f0.z); o.u[3] = f2bf(f0.w);
    o.u[4] = f2bf(f1.x); o.u[5] = f2bf(f1.y); o.u[6] = f2bf(f1.z); o.u[7] = f2bf(f1.w);
    *(bf16x8*)(dst + i) = o.v;
}

__launch_bounds__(512, 4)   // 4 waves/EU = 2 blocks/CU of 512 threads
__global__ void attn_tile_kernel(const float* __restrict__ qg,
                                 const unsigned short* __restrict__ kb,
                                 const float* __restrict__ vg,
                                 const float* __restrict__ bw,
                                 const int*   __restrict__ cp,
                                 const int*   __restrict__ mp,
                                 const int*   __restrict__ mask,
                                 float* __restrict__ o_out,
                                 float* __restrict__ a_out,
                                 float* __restrict__ p_out) {
    __shared__ __align__(16) float strip[TQ * STRIDE];        // 65664 B
    __shared__ __align__(16) float partials[4 * TQ * DD];     // 8192 B
    __shared__ __align__(16) unsigned short q_lds[16 * 72];   // 2304 B (rows TQ..15 zeroed)
    __shared__ float bwh[32];
    __shared__ float invl[TQ];
    // total ~76.3 KiB => 2 blocks/CU (was 147 KiB => 1 block/CU)

    const int tid = threadIdx.x;
    // XCD-aware swizzle: 4 heads per XCD share K/V in L2; q-tiles grouped so the
    // 4 heads of one q-tile run concurrently (mask rows shared across heads).
    const int x   = blockIdx.x;
    const int xcd = x & 7;
    const int s_  = x >> 3;              // 0..1023 per XCD
    const int bh  = xcd * 4 + (s_ & 3);  // 0..31
    const int qt  = s_ >> 2;             // 0..255
    const int b   = bh >> 4;
    const int h   = bh & 15;
    const int q0  = qt * TQ;

    const unsigned short* Kbase = kb + (size_t)bh * SS * DD;
    const float* Vbase = vg + (size_t)bh * SS * DD;

    // ---- stage Q tile (bf16, pre-scaled by 1/8 == exact pow2) + bias column ----
    {
        const float* Qrow = qg + ((size_t)bh * SS + q0) * DD;
        for (int e = tid; e < 16 * DD; e += 512) {
            int r = e >> 6, d = e & 63;
            q_lds[r * 72 + d] = (r < TQ) ? f2bf(Qrow[r * DD + d] * 0.125f)
                                         : (unsigned short)0;
        }
        if (tid < 32) bwh[tid] = bw[tid * HH + h];
    }
    __syncthreads();

    const int lane = tid & 63;
    const int wave = tid >> 6;
    const int quad = lane >> 4;
    const int l16  = lane & 15;

    // ---- Phase A: QK^T via MFMA 16x16x32 bf16 -> LDS strip (scaled scores) ----
    // B-operand comes straight from pre-converted bf16 K: no VALU conversion.
    {
        bf16x8 a0 = *(const bf16x8*)&q_lds[l16 * 72 + quad * 8];        // dims 0..31
        bf16x8 a1 = *(const bf16x8*)&q_lds[l16 * 72 + 32 + quad * 8];   // dims 32..63
        for (int ii = 0; ii < 16; ++ii) {
            const int kt = wave * 16 + ii;          // key tile of 16
            const unsigned short* kp = Kbase + (size_t)(kt * 16 + l16) * DD + quad * 8;
            bf16x8 b0 = *(const bf16x8*)(kp);
            bf16x8 b1 = *(const bf16x8*)(kp + 32);
            f32x4 acc = {0.f, 0.f, 0.f, 0.f};
            acc = __builtin_amdgcn_mfma_f32_16x16x32_bf16(a0, b0, acc, 0, 0, 0);
            acc = __builtin_amdgcn_mfma_f32_16x16x32_bf16(a1, b1, acc, 0, 0, 0);
            // C layout: row=(lane>>4)*4+reg, col=lane&15; rows >= TQ discarded
            if (quad < 2) {
                const int col = kt * 16 + l16;
                const int rb  = quad * 4;
                strip[(rb + 0) * STRIDE + col] = acc[0];
                strip[(rb + 1) * STRIDE + col] = acc[1];
                strip[(rb + 2) * STRIDE + col] = acc[2];
                strip[(rb + 3) * STRIDE + col] = acc[3];
            }
        }
    }
    __syncthreads();

    // ---- Phase B/C: one wave per q-row. bias+mask, row max, exp, sum ----
    {
        const int r  = wave;                 // 0..7
        const int i  = lane;                 // 0..63
        const int qi = q0 + r;
        const int cpq = cp[b * SS + qi];
        const int* mrow = mask + ((size_t)b * SS + qi) * SS;
        const int* mpb  = mp + b * SS;
        float* prow = p_out + ((size_t)bh * SS + qi) * SS;
        float* srow = strip + r * STRIDE;
        float mx = -3.0e38f;
        for (int j = 0; j < 8; ++j) {
            const int c0 = (i + 64 * j) * 4;     // 16B-vector per lane, coalesced
            i32x4 m4  = *(const i32x4*)(mrow + c0);
            i32x4 mp4 = *(const i32x4*)(mpb + c0);
            f32x4 s4  = *(const f32x4*)(srow + c0);
            f32x4 p4, sv;
            #pragma unroll
            for (int u = 0; u < 4; ++u) {
                p4[u] = bwh[rel_bucket(cpq, mp4[u])];
                float s = s4[u] + p4[u];
                if (m4[u] != 0) s = -1.0e9f;
                sv[u] = s;
                mx = fmaxf(mx, s);
            }
            *(f32x4*)(srow + c0) = sv;
            *(f32x4*)(prow + c0) = p4;
        }
        #pragma unroll
        for (int off = 32; off >= 1; off >>= 1)
            mx = fmaxf(mx, __shfl_xor(mx, off));
        float sum = 0.f;
        for (int j = 0; j < 8; ++j) {
            const int c0 = (i + 64 * j) * 4;
            f32x4 s4 = *(const f32x4*)(srow + c0);
            f32x4 e4;
            #pragma unroll
            for (int u = 0; u < 4; ++u) {
                e4[u] = __expf(s4[u] - mx);
                sum += e4[u];
            }
            *(f32x4*)(srow + c0) = e4;
        }
        #pragma unroll
        for (int off = 32; off >= 1; off >>= 1)
            sum += __shfl_xor(sum, off);
        if (i == 0) invl[r] = 1.0f / sum;
    }
    __syncthreads();

    // ---- Phase D: write attn = e * inv_l (f32x4, one row per iteration) ----
    {
        float* abase = a_out + ((size_t)bh * SS + q0) * SS;
        #pragma unroll
        for (int r = 0; r < TQ; ++r) {
            const float iv = invl[r];
            f32x4 s4 = *(const f32x4*)&strip[r * STRIDE + tid * 4];
            f32x4 o4;
            o4[0] = s4[0] * iv; o4[1] = s4[1] * iv;
            o4[2] = s4[2] * iv; o4[3] = s4[3] * iv;
            *(f32x4*)(abase + (size_t)r * SS + tid * 4) = o4;
        }
    }

    // ---- Phase E: PV (VALU fp32). wave -> (key quarter, row half of 4) ----
    {
        const int kc = wave & 3;
        const int rb = (wave >> 2) * 4;
        const int d  = lane;
        float acc0 = 0.f, acc1 = 0.f, acc2 = 0.f, acc3 = 0.f;
        const int cbeg = kc * 512;
        for (int c0 = cbeg; c0 < cbeg + 512; c0 += 4) {
            f32x4 e0 = *(const f32x4*)&strip[(rb + 0) * STRIDE + c0];  // broadcast
            f32x4 e1 = *(const f32x4*)&strip[(rb + 1) * STRIDE + c0];
            f32x4 e2 = *(const f32x4*)&strip[(rb + 2) * STRIDE + c0];
            f32x4 e3 = *(const f32x4*)&strip[(rb + 3) * STRIDE + c0];
            #pragma unroll
            for (int u = 0; u < 4; ++u) {
                const float vv = Vbase[(size_t)(c0 + u) * DD + d];     // coalesced
                acc0 += e0[u] * vv;
                acc1 += e1[u] * vv;
                acc2 += e2[u] * vv;
                acc3 += e3[u] * vv;
            }
        }
        partials[kc * (TQ * DD) + (rb + 0) * DD + d] = acc0;
        partials[kc * (TQ * DD) + (rb + 1) * DD + d] = acc1;
        partials[kc * (TQ * DD) + (rb + 2) * DD + d] = acc2;
        partials[kc * (TQ * DD) + (rb + 3) * DD + d] = acc3;
    }
    __syncthreads();

    // ---- reduce partials over 4 key-quarters, apply 1/l, write out ----
    {
        const int r = tid >> 6;                       // 512 threads = TQ*DD elems
        const float v = partials[tid] + partials[512 + tid] +
                        partials[1024 + tid] + partials[1536 + tid];
        o_out[((size_t)bh * SS + q0 + r) * DD + (tid & 63)] = v * invl[r];
    }
}

extern "C" void kernel_launch(void* const* d_in, const int* in_sizes, int n_in,
                              void* d_out, int out_size, void* d_ws, size_t ws_size,
                              hipStream_t stream) {
    const float* q  = (const float*)d_in[0];
    const float* k  = (const float*)d_in[1];
    const float* v  = (const float*)d_in[2];
    const float* bw = (const float*)d_in[3];
    const int*   cp = (const int*)d_in[4];
    const int*   mp = (const int*)d_in[5];
    const int*   mask = (const int*)d_in[6];

    float* o_out = (float*)d_out;                                   // [B,H,S,D]
    float* a_out = o_out + (size_t)BB * HH * SS * DD;               // [B,H,S,S]
    float* p_out = a_out + (size_t)BB * HH * SS * SS;               // [B,H,S,S]

    // bf16 K lives in workspace (8 MiB)
    unsigned short* kb = (unsigned short*)d_ws;
    const int conv_grid = (BB * HH * SS * DD) / (8 * 256);   // 2048 blocks, exact
    conv_k_bf16<<<conv_grid, 256, 0, stream>>>(k, kb);

    const int grid = BB * HH * (SS / TQ);   // 8192 blocks, one per (b,h,q-tile)
    attn_tile_kernel<<<grid, 512, 0, stream>>>(q, kb, v, bw, cp, mp, mask,
                                               o_out, a_out, p_out);
}